// Round 2
// baseline (784.794 us; speedup 1.0000x reference)
//
#include <hip/hip_runtime.h>

#define NBATCH 256
#define P 1024
#define Q 128
#define NS_ITERS 11

// ---------------------------------------------------------------------------
// Kernel 1: gram[n] = temp^T * temp, temp = X - lr*G computed on the fly.
// ---------------------------------------------------------------------------
__global__ __launch_bounds__(256) void gram_kernel(
    const float* __restrict__ X, const float* __restrict__ G,
    const float* __restrict__ lrp, float* __restrict__ gram)
{
    const int n = blockIdx.x;
    const float lr = *lrp;
    const float* xb = X + (size_t)n * P * Q;
    const float* gb = G + (size_t)n * P * Q;
    __shared__ float sT[32][Q];  // 16 KB
    const int tid = threadIdx.x;
    const int ty = tid >> 4, tx = tid & 15;

    float acc[8][8];
#pragma unroll
    for (int i = 0; i < 8; ++i)
#pragma unroll
        for (int j = 0; j < 8; ++j) acc[i][j] = 0.0f;

    for (int p0 = 0; p0 < P; p0 += 32) {
#pragma unroll
        for (int t = 0; t < 4; ++t) {
            const int idx = tid + t * 256;
            float4 xv = reinterpret_cast<const float4*>(xb + (size_t)p0 * Q)[idx];
            float4 gv = reinterpret_cast<const float4*>(gb + (size_t)p0 * Q)[idx];
            float4 tv;
            tv.x = xv.x - lr * gv.x; tv.y = xv.y - lr * gv.y;
            tv.z = xv.z - lr * gv.z; tv.w = xv.w - lr * gv.w;
            reinterpret_cast<float4*>(&sT[0][0])[idx] = tv;
        }
        __syncthreads();
        for (int p = 0; p < 32; ++p) {
            float4 a0 = *reinterpret_cast<const float4*>(&sT[p][ty * 8]);
            float4 a1 = *reinterpret_cast<const float4*>(&sT[p][ty * 8 + 4]);
            float4 b0 = *reinterpret_cast<const float4*>(&sT[p][tx * 8]);
            float4 b1 = *reinterpret_cast<const float4*>(&sT[p][tx * 8 + 4]);
            float a[8] = {a0.x, a0.y, a0.z, a0.w, a1.x, a1.y, a1.z, a1.w};
            float b[8] = {b0.x, b0.y, b0.z, b0.w, b1.x, b1.y, b1.z, b1.w};
#pragma unroll
            for (int i = 0; i < 8; ++i)
#pragma unroll
                for (int j = 0; j < 8; ++j) acc[i][j] += a[i] * b[j];
        }
        __syncthreads();
    }
    float* gm = gram + (size_t)n * Q * Q;
#pragma unroll
    for (int i = 0; i < 8; ++i) {
#pragma unroll
        for (int j = 0; j < 2; ++j) {
            float4 v = make_float4(acc[i][4 * j + 0], acc[i][4 * j + 1],
                                   acc[i][4 * j + 2], acc[i][4 * j + 3]);
            reinterpret_cast<float4*>(&gm[(size_t)(ty * 8 + i) * Q + tx * 8])[j] = v;
        }
    }
}

// ---------------------------------------------------------------------------
// Kernel 2: Newton-Schulz inverse sqrt, coupled form.
// State: Z (-> A^{-1/2}), W = A*Z^2 (-> I). T = 1.5I - 0.5W.
//   Z <- T*Z            (1 GEMM)
//   W <- T*W*T          (2 GEMMs, quartered through sM scratch)
// A = gram/||gram||_F so eigs(A) in (0,1] -> unconditional convergence.
// Zout = Z / sqrt(c). All operands symmetric -> row-wise float4 LDS reads.
// LDS: sZ 64K + sW 64K + sM 16K = 147 KB -> 1 block/CU.
// ---------------------------------------------------------------------------
__global__ __launch_bounds__(256) void ns_kernel(
    const float* __restrict__ gram, float* __restrict__ Zout)
{
    const int n = blockIdx.x;
    const float* gm = gram + (size_t)n * Q * Q;
    __shared__ float sZ[Q][Q];     // Z iterate (symmetric)
    __shared__ float sW[Q][Q];     // W = A Z^2 (symmetric)
    __shared__ float sM[32][Q];    // quarter scratch M = (T W)[32q:32q+32, :]
    __shared__ float sRed[4];
    const int tid = threadIdx.x;
    const int ty = tid >> 4, tx = tid & 15;    // 16x16 grid, 8x8 tiles (Z GEMM)
    const int tyq = tid >> 5, txq = tid & 31;  // 8x32 grid, 4x4 tiles (W GEMMs)

    // ---- load gram -> sW, Frobenius norm ----
    float ss = 0.0f;
#pragma unroll
    for (int t = 0; t < 16; ++t) {
        const int idx = tid + t * 256;
        float4 v = reinterpret_cast<const float4*>(gm)[idx];
        reinterpret_cast<float4*>(&sW[0][0])[idx] = v;
        ss += v.x * v.x + v.y * v.y + v.z * v.z + v.w * v.w;
    }
#pragma unroll
    for (int off = 32; off > 0; off >>= 1) ss += __shfl_down(ss, off, 64);
    if ((tid & 63) == 0) sRed[tid >> 6] = ss;
    __syncthreads();
    const float c = sqrtf(sRed[0] + sRed[1] + sRed[2] + sRed[3]);
    const float rc = 1.0f / c;

    // ---- W = gram/c (own elements: no hazard); Z = T0 = 1.5I - 0.5W ----
#pragma unroll
    for (int t = 0; t < 16; ++t) {
        const int idx = tid + t * 256;
        float4 v = reinterpret_cast<float4*>(&sW[0][0])[idx];
        v.x *= rc; v.y *= rc; v.z *= rc; v.w *= rc;
        reinterpret_cast<float4*>(&sW[0][0])[idx] = v;
        float4 z = make_float4(-0.5f * v.x, -0.5f * v.y, -0.5f * v.z, -0.5f * v.w);
        const int e = idx * 4;
        const int d = (e >> 7) - (e & 127);
        if (d == 0) z.x += 1.5f; else if (d == 1) z.y += 1.5f;
        else if (d == 2) z.z += 1.5f; else if (d == 3) z.w += 1.5f;
        reinterpret_cast<float4*>(&sZ[0][0])[idx] = z;
    }
    __syncthreads();

    for (int it = 1; it < NS_ITERS; ++it) {
        // ================= W <- T W T, in 4 row-quarters =================
        float wnew[4][4][4];  // [quarter][i][j], all compile-time indexed
#pragma unroll
        for (int q = 0; q < 4; ++q) {
            // phase A_q: M = (T W)[rows 32q..32q+32) = 1.5 W - 0.5 W*W
            float acc[4][4];
#pragma unroll
            for (int i = 0; i < 4; ++i)
#pragma unroll
                for (int j = 0; j < 4; ++j) acc[i][j] = 0.0f;
            for (int k = 0; k < Q; ++k) {
                float4 a4 = *reinterpret_cast<const float4*>(&sW[k][q * 32 + tyq * 4]);
                float4 b4 = *reinterpret_cast<const float4*>(&sW[k][txq * 4]);
                float a[4] = {a4.x, a4.y, a4.z, a4.w};
                float b[4] = {b4.x, b4.y, b4.z, b4.w};
#pragma unroll
                for (int i = 0; i < 4; ++i)
#pragma unroll
                    for (int j = 0; j < 4; ++j) acc[i][j] += a[i] * b[j];
            }
#pragma unroll
            for (int i = 0; i < 4; ++i) {
                float4 w4 = *reinterpret_cast<const float4*>(&sW[q * 32 + tyq * 4 + i][txq * 4]);
                float4 m4 = make_float4(1.5f * w4.x - 0.5f * acc[i][0],
                                        1.5f * w4.y - 0.5f * acc[i][1],
                                        1.5f * w4.z - 0.5f * acc[i][2],
                                        1.5f * w4.w - 0.5f * acc[i][3]);
                *reinterpret_cast<float4*>(&sM[tyq * 4 + i][txq * 4]) = m4;
            }
            __syncthreads();  // M quarter visible

            // phase B_q: Wnew_q = 1.5 M - 0.5 M*W  (M rows read directly)
            float acc2[4][4];
#pragma unroll
            for (int i = 0; i < 4; ++i)
#pragma unroll
                for (int j = 0; j < 4; ++j) acc2[i][j] = 0.0f;
            for (int k0 = 0; k0 < Q; k0 += 4) {
                float4 am[4], bb[4];
#pragma unroll
                for (int i = 0; i < 4; ++i)
                    am[i] = *reinterpret_cast<const float4*>(&sM[tyq * 4 + i][k0]);
#pragma unroll
                for (int dk = 0; dk < 4; ++dk)
                    bb[dk] = *reinterpret_cast<const float4*>(&sW[k0 + dk][txq * 4]);
#pragma unroll
                for (int i = 0; i < 4; ++i) {
                    float amv[4] = {am[i].x, am[i].y, am[i].z, am[i].w};
#pragma unroll
                    for (int dk = 0; dk < 4; ++dk) {
                        float bv[4] = {bb[dk].x, bb[dk].y, bb[dk].z, bb[dk].w};
#pragma unroll
                        for (int j = 0; j < 4; ++j) acc2[i][j] += amv[dk] * bv[j];
                    }
                }
            }
#pragma unroll
            for (int i = 0; i < 4; ++i) {
                float4 m4 = *reinterpret_cast<const float4*>(&sM[tyq * 4 + i][txq * 4]);
                wnew[q][i][0] = 1.5f * m4.x - 0.5f * acc2[i][0];
                wnew[q][i][1] = 1.5f * m4.y - 0.5f * acc2[i][1];
                wnew[q][i][2] = 1.5f * m4.z - 0.5f * acc2[i][2];
                wnew[q][i][3] = 1.5f * m4.w - 0.5f * acc2[i][3];
            }
            __syncthreads();  // sM reads done; next quarter may overwrite
        }
        // phase E: commit W_new (all reads of old W finished above)
#pragma unroll
        for (int q = 0; q < 4; ++q)
#pragma unroll
            for (int i = 0; i < 4; ++i) {
                float4 v = make_float4(wnew[q][i][0], wnew[q][i][1],
                                       wnew[q][i][2], wnew[q][i][3]);
                *reinterpret_cast<float4*>(&sW[q * 32 + tyq * 4 + i][txq * 4]) = v;
            }
        __syncthreads();

        // ================= Z <- T Z = 1.5 Z - 0.5 W Z =================
        float acc[8][8];
#pragma unroll
        for (int i = 0; i < 8; ++i)
#pragma unroll
            for (int j = 0; j < 8; ++j) acc[i][j] = 0.0f;
        for (int k = 0; k < Q; ++k) {
            float4 a0 = *reinterpret_cast<const float4*>(&sW[k][ty * 8]);
            float4 a1 = *reinterpret_cast<const float4*>(&sW[k][ty * 8 + 4]);
            float4 b0 = *reinterpret_cast<const float4*>(&sZ[k][tx * 8]);
            float4 b1 = *reinterpret_cast<const float4*>(&sZ[k][tx * 8 + 4]);
            float a[8] = {a0.x, a0.y, a0.z, a0.w, a1.x, a1.y, a1.z, a1.w};
            float b[8] = {b0.x, b0.y, b0.z, b0.w, b1.x, b1.y, b1.z, b1.w};
#pragma unroll
            for (int i = 0; i < 8; ++i)
#pragma unroll
                for (int j = 0; j < 8; ++j) acc[i][j] += a[i] * b[j];
        }
        // combine with own Z tile in-place in acc (reads sZ before overwrite)
#pragma unroll
        for (int i = 0; i < 8; ++i) {
            const int r = ty * 8 + i;
            float4 z0 = *reinterpret_cast<const float4*>(&sZ[r][tx * 8]);
            float4 z1 = *reinterpret_cast<const float4*>(&sZ[r][tx * 8 + 4]);
            acc[i][0] = 1.5f * z0.x - 0.5f * acc[i][0];
            acc[i][1] = 1.5f * z0.y - 0.5f * acc[i][1];
            acc[i][2] = 1.5f * z0.z - 0.5f * acc[i][2];
            acc[i][3] = 1.5f * z0.w - 0.5f * acc[i][3];
            acc[i][4] = 1.5f * z1.x - 0.5f * acc[i][4];
            acc[i][5] = 1.5f * z1.y - 0.5f * acc[i][5];
            acc[i][6] = 1.5f * z1.z - 0.5f * acc[i][6];
            acc[i][7] = 1.5f * z1.w - 0.5f * acc[i][7];
        }
        __syncthreads();  // everyone done reading old Z
#pragma unroll
        for (int i = 0; i < 8; ++i) {
            const int r = ty * 8 + i;
            *reinterpret_cast<float4*>(&sZ[r][tx * 8]) =
                make_float4(acc[i][0], acc[i][1], acc[i][2], acc[i][3]);
            *reinterpret_cast<float4*>(&sZ[r][tx * 8 + 4]) =
                make_float4(acc[i][4], acc[i][5], acc[i][6], acc[i][7]);
        }
        __syncthreads();
    }

    // ---- Zout = Z / sqrt(c):  S^{-1/2} = (A*c)^{-1/2} = Z/sqrt(c) ----
    const float rs = 1.0f / sqrtf(c);
    float* zo = Zout + (size_t)n * Q * Q;
#pragma unroll
    for (int t = 0; t < 16; ++t) {
        const int idx = tid + t * 256;
        float4 v = reinterpret_cast<float4*>(&sZ[0][0])[idx];
        v.x *= rs; v.y *= rs; v.z *= rs; v.w *= rs;
        reinterpret_cast<float4*>(zo)[idx] = v;
    }
}

// ---------------------------------------------------------------------------
// Kernel 3: out[n] = temp[n] @ Zout[n]. 8 blocks per batch (128 P-rows each).
// ---------------------------------------------------------------------------
__global__ __launch_bounds__(256) void apply_kernel(
    const float* __restrict__ X, const float* __restrict__ G,
    const float* __restrict__ lrp, const float* __restrict__ Z,
    float* __restrict__ out)
{
    const int n = blockIdx.x >> 3;
    const int p0 = (blockIdx.x & 7) * 128;
    const float lr = *lrp;
    const float* xb = X + (size_t)n * P * Q + (size_t)p0 * Q;
    const float* gb = G + (size_t)n * P * Q + (size_t)p0 * Q;
    float* ob = out + (size_t)n * P * Q + (size_t)p0 * Q;
    const float* zb = Z + (size_t)n * Q * Q;

    __shared__ float sT[128][Q + 1];
    __shared__ float sZ[Q][Q];
    const int tid = threadIdx.x;
    const int ty = tid >> 4, tx = tid & 15;

#pragma unroll
    for (int t = 0; t < 16; ++t) {
        const int idx = tid + t * 256;
        reinterpret_cast<float4*>(&sZ[0][0])[idx] =
            reinterpret_cast<const float4*>(zb)[idx];
    }
#pragma unroll
    for (int t = 0; t < 16; ++t) {
        const int idx = tid + t * 256;
        const int p = idx >> 5, q4 = idx & 31;
        float4 xv = reinterpret_cast<const float4*>(xb + (size_t)p * Q)[q4];
        float4 gv = reinterpret_cast<const float4*>(gb + (size_t)p * Q)[q4];
        sT[p][q4 * 4 + 0] = xv.x - lr * gv.x;
        sT[p][q4 * 4 + 1] = xv.y - lr * gv.y;
        sT[p][q4 * 4 + 2] = xv.z - lr * gv.z;
        sT[p][q4 * 4 + 3] = xv.w - lr * gv.w;
    }
    __syncthreads();

    float acc[8][8];
#pragma unroll
    for (int i = 0; i < 8; ++i)
#pragma unroll
        for (int j = 0; j < 8; ++j) acc[i][j] = 0.0f;

    for (int q = 0; q < Q; ++q) {
        float a[8];
#pragma unroll
        for (int i = 0; i < 8; ++i) a[i] = sT[ty * 8 + i][q];
        float4 b0 = *reinterpret_cast<const float4*>(&sZ[q][tx * 8]);
        float4 b1 = *reinterpret_cast<const float4*>(&sZ[q][tx * 8 + 4]);
        float b[8] = {b0.x, b0.y, b0.z, b0.w, b1.x, b1.y, b1.z, b1.w};
#pragma unroll
        for (int i = 0; i < 8; ++i)
#pragma unroll
            for (int j = 0; j < 8; ++j) acc[i][j] += a[i] * b[j];
    }

#pragma unroll
    for (int i = 0; i < 8; ++i) {
#pragma unroll
        for (int j = 0; j < 2; ++j) {
            float4 v = make_float4(acc[i][4 * j + 0], acc[i][4 * j + 1],
                                   acc[i][4 * j + 2], acc[i][4 * j + 3]);
            reinterpret_cast<float4*>(&ob[(size_t)(ty * 8 + i) * Q + tx * 8])[j] = v;
        }
    }
}

extern "C" void kernel_launch(void* const* d_in, const int* in_sizes, int n_in,
                              void* d_out, int out_size, void* d_ws, size_t ws_size,
                              hipStream_t stream) {
    const float* X  = (const float*)d_in[0];
    const float* G  = (const float*)d_in[1];
    const float* lr = (const float*)d_in[2];
    float* out  = (float*)d_out;
    float* gram = (float*)d_ws;
    float* Z    = gram + (size_t)NBATCH * Q * Q;

    gram_kernel<<<NBATCH, 256, 0, stream>>>(X, G, lr, gram);
    ns_kernel<<<NBATCH, 256, 0, stream>>>(gram, Z);
    apply_kernel<<<NBATCH * 8, 256, 0, stream>>>(X, G, lr, Z, out);
}